// Round 7
// baseline (292.428 us; speedup 1.0000x reference)
//
#include <hip/hip_runtime.h>
#include <hip/hip_bf16.h>

// Problem constants
#define DIMD   1024
#define BATCH  4
#define SEQ    4096
#define NTOK   (BATCH * SEQ)   // 16384
#define CHUNK  64              // recurrence chunk length
#define NCHUNK (SEQ / CHUNK)   // 64

// K-tiling for the MFMA GEMMs: 64-deep K tiles, 16 tiles total.
#define KBK    64
#define NKT    (DIMD / KBK)

typedef unsigned short ushort_t;
typedef __attribute__((ext_vector_type(8))) __bf16   bf16x8;
typedef __attribute__((ext_vector_type(4))) float    f32x4;
typedef __attribute__((ext_vector_type(8))) ushort_t u16x8;
typedef __attribute__((ext_vector_type(4))) ushort_t u16x4;

__device__ __forceinline__ float b2f(ushort_t u) {
    union { unsigned int i; float f; } x;
    x.i = ((unsigned int)u) << 16;
    return x.f;
}

__device__ __forceinline__ ushort_t f2b(float f) {
    union { float f; unsigned int i; } x;
    x.f = f;
    unsigned int r = x.i + 0x7fffu + ((x.i >> 16) & 1u);  // RNE
    return (ushort_t)(r >> 16);
}

// 16B global->LDS direct copy. LDS dest must be wave-uniform-base + lane*16
// (linear); swizzling is done on the per-lane GLOBAL source address.
#define GLL(gsrc, ldst) __builtin_amdgcn_global_load_lds( \
    (__attribute__((address_space(1))) void*)(gsrc), \
    (__attribute__((address_space(3))) void*)(ldst), 16, 0, 0)

// ---------------------------------------------------------------------------
// All f32->bf16 conversions in ONE launch, fully contiguous:
// one float4 load -> one u16x4 store per thread. Bit-identical output.
// ---------------------------------------------------------------------------
__global__ __launch_bounds__(256)
void conv_all(const float* __restrict__ x,
              const float* __restrict__ W0, const float* __restrict__ W1,
              const float* __restrict__ W2, const float* __restrict__ W3,
              ushort_t* __restrict__ xb, ushort_t* __restrict__ wb)
{
    const long long i = (long long)blockIdx.x * 256 + threadIdx.x;  // float4 idx
    const long long NX = (long long)NTOK * DIMD / 4;                // 4194304
    const float4* s4;
    ushort_t* dst;
    long long j;
    if (i < NX) {
        s4 = (const float4*)x; j = i; dst = xb;
    } else {
        const long long wj = i - NX;              // < 1048576
        const int m = (int)(wj >> 18);            // 262144 float4 / matrix
        j  = wj & 262143;
        s4 = (const float4*)((m == 0) ? W0 : (m == 1) ? W1 : (m == 2) ? W2 : W3);
        dst = wb + (size_t)m * DIMD * DIMD;
    }
    const float4 a = s4[j];
    u16x4 o;
    o[0] = f2b(a.x); o[1] = f2b(a.y); o[2] = f2b(a.z); o[3] = f2b(a.w);
    *(u16x4*)(dst + j * 4) = o;
}

// ---------------------------------------------------------------------------
// Fused 3-projection GEMM: k, v, r in one block (A staged ONCE for all 3).
// Block 256 rows x 128 cols, 512 threads (8 waves, 4M x 2N; wave owns a
// 64x64 tile of EACH matrix -> 48 f32x4 accumulators). Grid 64x8 = 512
// blocks = 2 rounds at 1 block/CU. LDS 160 KB: A 2x32K, Bk/Bv/Br 2x16K.
// 6 phases/K-tile x 16 MFMA, counted vmcnt(4) (A prefetched 2 tiles ahead,
// B one ahead), XOR swizzle on global source + LDS read (involution).
// Accumulation order over k identical to previous rounds -> bit-identical.
// ---------------------------------------------------------------------------
__global__ __launch_bounds__(512, 2)
void gemm_kvr3(const ushort_t* __restrict__ A,
               const ushort_t* __restrict__ Wk,
               const ushort_t* __restrict__ Wv,
               const ushort_t* __restrict__ Wr,
               const float* __restrict__ td,
               ushort_t* __restrict__ Okv,
               ushort_t* __restrict__ Or,
               float* __restrict__ cs)
{
    __shared__ __align__(16) ushort_t smem[81920];   // 160 KB exactly

    ushort_t* As0 = smem;                 // 16384 elts each (32 KB)
    ushort_t* As1 = smem + 16384;
    ushort_t* Bk0 = smem + 32768;         // 8192 elts each (16 KB)
    ushort_t* Bk1 = smem + 40960;
    ushort_t* Bv0 = smem + 49152;
    ushort_t* Bv1 = smem + 57344;
    ushort_t* Br0 = smem + 65536;
    ushort_t* Br1 = smem + 73728;

    const int tid  = threadIdx.x;
    const int lane = tid & 63;
    const int wv   = tid >> 6;        // 0..7
    const int wr   = wv >> 1;         // 0..3 : 64-row chunk (= seq chunk)
    const int wc   = wv & 1;          // 0..1 : 64-col half
    const int lrow = lane & 15;
    const int kq   = lane >> 4;
    const int s8   = lrow & 7;
    const int sw0  = (kq ^ s8) * 8;        // swizzled elem offset, ksub=0
    const int sw1  = ((kq + 4) ^ s8) * 8;  // swizzled elem offset, ksub=1

    // Staging geometry: dest chunk (row, q) <- global (row, q ^ (row&7)).
    const int r_  = tid >> 3;                       // 0..63
    const int q_  = ((tid & 7) ^ (r_ & 7)) * 8;

    const int row0 = blockIdx.x * 256;              // 64 row-panels
    const int e0   = blockIdx.y * 128;              // 8 col-panels

    const size_t aoffs = (size_t)(row0 + r_) * DIMD + q_;
    const size_t boffs = (size_t)(e0 + r_) * DIMD + q_;

#define K3_STAGE_A(dst, k0) do { \
    _Pragma("unroll") \
    for (int it_ = 0; it_ < 4; ++it_) \
        GLL(A + aoffs + (size_t)it_ * 64 * DIMD + (k0), \
            (char*)(dst) + (tid + it_ * 512) * 16); \
} while (0)

#define K3_STAGE_B(Wp, dst, k0) do { \
    _Pragma("unroll") \
    for (int it_ = 0; it_ < 2; ++it_) \
        GLL((Wp) + boffs + (size_t)it_ * 64 * DIMD + (k0), \
            (char*)(dst) + (tid + it_ * 512) * 16); \
} while (0)

    f32x4 ak[4][4], av[4][4], ar[4][4];
#pragma unroll
    for (int i = 0; i < 4; i++)
#pragma unroll
        for (int j = 0; j < 4; j++) {
            ak[i][j] = f32x4{0.f, 0.f, 0.f, 0.f};
            av[i][j] = f32x4{0.f, 0.f, 0.f, 0.f};
            ar[i][j] = f32x4{0.f, 0.f, 0.f, 0.f};
        }

    // Prologue: A0 + Bk/Bv/Br(0) + A1 in flight; drain tile0, keep A1.
    K3_STAGE_A(As0, 0);
    K3_STAGE_B(Wk, Bk0, 0);
    K3_STAGE_B(Wv, Bv0, 0);
    K3_STAGE_B(Wr, Br0, 0);
    asm volatile("" ::: "memory");
    K3_STAGE_A(As1, KBK);
    asm volatile("s_waitcnt vmcnt(4)" ::: "memory");
    __builtin_amdgcn_s_barrier();

    auto tile = [&](int kt, ushort_t* Asb,
                    ushort_t* Bkb, ushort_t* Bvb, ushort_t* Brb,
                    ushort_t* Bkn, ushort_t* Bvn, ushort_t* Brn) {
        bf16x8 af0[4], af1[4], bk0[4], bk1[4], bv0[4], bv1[4], br0[4], br1[4];

        // ---- P0: read A s0 + Bk s0; stage Bk(t+1); 16 MFMA k-s0
#pragma unroll
        for (int i = 0; i < 4; i++)
            af0[i] = *(const bf16x8*)(Asb + (wr * 64 + i * 16 + lrow) * KBK + sw0);
#pragma unroll
        for (int j = 0; j < 4; j++)
            bk0[j] = *(const bf16x8*)(Bkb + (wc * 64 + j * 16 + lrow) * KBK + sw0);
        if (kt + 1 < NKT) K3_STAGE_B(Wk, Bkn, (kt + 1) * KBK);
        __builtin_amdgcn_s_barrier();
        asm volatile("s_waitcnt lgkmcnt(0)" ::: "memory");
        __builtin_amdgcn_sched_barrier(0);
        __builtin_amdgcn_s_setprio(1);
#pragma unroll
        for (int i = 0; i < 4; i++)
#pragma unroll
            for (int j = 0; j < 4; j++)
                ak[i][j] = __builtin_amdgcn_mfma_f32_16x16x32_bf16(af0[i], bk0[j], ak[i][j], 0, 0, 0);
        __builtin_amdgcn_s_setprio(0);
        __builtin_amdgcn_s_barrier();

        // ---- P1: read Bv s0; stage Bv(t+1); 16 MFMA v-s0
#pragma unroll
        for (int j = 0; j < 4; j++)
            bv0[j] = *(const bf16x8*)(Bvb + (wc * 64 + j * 16 + lrow) * KBK + sw0);
        if (kt + 1 < NKT) K3_STAGE_B(Wv, Bvn, (kt + 1) * KBK);
        __builtin_amdgcn_s_barrier();
        asm volatile("s_waitcnt lgkmcnt(0)" ::: "memory");
        __builtin_amdgcn_sched_barrier(0);
        __builtin_amdgcn_s_setprio(1);
#pragma unroll
        for (int i = 0; i < 4; i++)
#pragma unroll
            for (int j = 0; j < 4; j++)
                av[i][j] = __builtin_amdgcn_mfma_f32_16x16x32_bf16(af0[i], bv0[j], av[i][j], 0, 0, 0);
        __builtin_amdgcn_s_setprio(0);
        __builtin_amdgcn_s_barrier();

        // ---- P2: read Br s0; stage Br(t+1); 16 MFMA r-s0
#pragma unroll
        for (int j = 0; j < 4; j++)
            br0[j] = *(const bf16x8*)(Brb + (wc * 64 + j * 16 + lrow) * KBK + sw0);
        if (kt + 1 < NKT) K3_STAGE_B(Wr, Brn, (kt + 1) * KBK);
        __builtin_amdgcn_s_barrier();
        asm volatile("s_waitcnt lgkmcnt(0)" ::: "memory");
        __builtin_amdgcn_sched_barrier(0);
        __builtin_amdgcn_s_setprio(1);
#pragma unroll
        for (int i = 0; i < 4; i++)
#pragma unroll
            for (int j = 0; j < 4; j++)
                ar[i][j] = __builtin_amdgcn_mfma_f32_16x16x32_bf16(af0[i], br0[j], ar[i][j], 0, 0, 0);
        __builtin_amdgcn_s_setprio(0);
        __builtin_amdgcn_s_barrier();

        // ---- P3: read A s1 + Bk s1; 16 MFMA k-s1 (A buffer fully read after)
#pragma unroll
        for (int i = 0; i < 4; i++)
            af1[i] = *(const bf16x8*)(Asb + (wr * 64 + i * 16 + lrow) * KBK + sw1);
#pragma unroll
        for (int j = 0; j < 4; j++)
            bk1[j] = *(const bf16x8*)(Bkb + (wc * 64 + j * 16 + lrow) * KBK + sw1);
        __builtin_amdgcn_s_barrier();
        asm volatile("s_waitcnt lgkmcnt(0)" ::: "memory");
        __builtin_amdgcn_sched_barrier(0);
        __builtin_amdgcn_s_setprio(1);
#pragma unroll
        for (int i = 0; i < 4; i++)
#pragma unroll
            for (int j = 0; j < 4; j++)
                ak[i][j] = __builtin_amdgcn_mfma_f32_16x16x32_bf16(af1[i], bk1[j], ak[i][j], 0, 0, 0);
        __builtin_amdgcn_s_setprio(0);
        __builtin_amdgcn_s_barrier();

        // ---- P4: read Bv s1; stage A(t+2) into vacated A buffer
        //      (all A reads done at P3 lgkm + barrier); 16 MFMA v-s1
#pragma unroll
        for (int j = 0; j < 4; j++)
            bv1[j] = *(const bf16x8*)(Bvb + (wc * 64 + j * 16 + lrow) * KBK + sw1);
        if (kt + 2 < NKT) K3_STAGE_A(Asb, (kt + 2) * KBK);
        __builtin_amdgcn_s_barrier();
        asm volatile("s_waitcnt lgkmcnt(0)" ::: "memory");
        __builtin_amdgcn_sched_barrier(0);
        __builtin_amdgcn_s_setprio(1);
#pragma unroll
        for (int i = 0; i < 4; i++)
#pragma unroll
            for (int j = 0; j < 4; j++)
                av[i][j] = __builtin_amdgcn_mfma_f32_16x16x32_bf16(af1[i], bv1[j], av[i][j], 0, 0, 0);
        __builtin_amdgcn_s_setprio(0);
        __builtin_amdgcn_s_barrier();

        // ---- P5: read Br s1; 16 MFMA r-s1; counted-vmcnt tile boundary
#pragma unroll
        for (int j = 0; j < 4; j++)
            br1[j] = *(const bf16x8*)(Brb + (wc * 64 + j * 16 + lrow) * KBK + sw1);
        __builtin_amdgcn_s_barrier();
        asm volatile("s_waitcnt lgkmcnt(0)" ::: "memory");
        __builtin_amdgcn_sched_barrier(0);
        __builtin_amdgcn_s_setprio(1);
#pragma unroll
        for (int i = 0; i < 4; i++)
#pragma unroll
            for (int j = 0; j < 4; j++)
                ar[i][j] = __builtin_amdgcn_mfma_f32_16x16x32_bf16(af1[i], br1[j], ar[i][j], 0, 0, 0);
        __builtin_amdgcn_s_setprio(0);
        // Drain B(t+1) (6 loads); keep A(t+2) (newest 4) in flight.
        if (kt < NKT - 2)       asm volatile("s_waitcnt vmcnt(4)" ::: "memory");
        else if (kt == NKT - 2) asm volatile("s_waitcnt vmcnt(0)" ::: "memory");
        __builtin_amdgcn_s_barrier();
    };

    for (int m = 0; m < NKT / 2; ++m) {
        tile(2 * m,     As0, Bk0, Bv0, Br0, Bk1, Bv1, Br1);
        tile(2 * m + 1, As1, Bk1, Bv1, Br1, Bk0, Bv0, Br0);
    }

    // Epilogue 1: kv + sigmoid(r) stores. C/D: col = lane&15, row = kq*4+reg.
#pragma unroll
    for (int i = 0; i < 4; i++)
#pragma unroll
        for (int j = 0; j < 4; j++)
#pragma unroll
            for (int r = 0; r < 4; r++) {
                const int row = row0 + wr * 64 + i * 16 + kq * 4 + r;
                const int col = e0 + wc * 64 + j * 16 + lrow;
                const size_t o = (size_t)row * DIMD + col;
                Okv[o] = f2b(ak[i][j][r] * av[i][j][r]);
                Or[o]  = f2b(1.f / (1.f + __expf(-ar[i][j][r])));
            }

    // Epilogue 2: per-chunk weighted sum s(d) = sum_row decay^(63-row) k*v.
    // Wave wr owns exactly one 64-token chunk.
#pragma unroll
    for (int j = 0; j < 4; j++) {
        const int col = e0 + wc * 64 + j * 16 + lrow;
        const float w = -__expf(td[col]);
        float s = 0.f;
#pragma unroll
        for (int i = 0; i < 4; i++)
#pragma unroll
            for (int r = 0; r < 4; r++) {
                const int rl = i * 16 + kq * 4 + r;           // 0..63
                s += __expf(w * (float)(63 - rl)) * ak[i][j][r] * av[i][j][r];
            }
        s += __shfl_xor(s, 16);
        s += __shfl_xor(s, 32);
        if (kq == 0) {
            const int gchunk = (row0 >> 6) + wr;              // global chunk id
            cs[(size_t)gchunk * DIMD + col] = s;
        }
    }
#undef K3_STAGE_A
#undef K3_STAGE_B
}

// ---------------------------------------------------------------------------
// Final GEMM: C[n,e] = sum_d A[n,d] * W[e,d], f32 out.
// 256x256 block, 512 threads, 4-phase counted-vmcnt pipeline + swizzle.
// ---------------------------------------------------------------------------
__global__ __launch_bounds__(512, 2)
void gemm_bt(const ushort_t* __restrict__ A,
             const ushort_t* __restrict__ W,
             float* __restrict__ Of)
{
    __shared__ __align__(16) ushort_t As[2][256 * KBK];  // 2 x 32 KB
    __shared__ __align__(16) ushort_t Bs[2][256 * KBK];  // 2 x 32 KB

    const int tid  = threadIdx.x;
    const int lane = tid & 63;
    const int wv   = tid >> 6;
    const int wr   = wv >> 2;
    const int wc   = wv & 3;
    const int lrow = lane & 15;
    const int kq   = lane >> 4;
    const int s8   = lrow & 7;
    const int sw0  = (kq ^ s8) * 8;
    const int sw1  = ((kq + 4) ^ s8) * 8;

    const int row0 = blockIdx.x * 256;
    const int e0   = blockIdx.y * 256;

    const int r_  = tid >> 3;
    const int q_  = ((tid & 7) ^ (r_ & 7)) * 8;
    const size_t aoffs = (size_t)(row0 + r_) * DIMD + q_;
    const size_t boffs = (size_t)(e0 + r_) * DIMD + q_;

#define BT_STAGE_A(dst, k0) do { \
    _Pragma("unroll") \
    for (int it_ = 0; it_ < 4; ++it_) \
        GLL(A + aoffs + (size_t)it_ * 64 * DIMD + (k0), \
            (char*)(dst) + (tid + it_ * 512) * 16); \
} while (0)

#define BT_STAGE_B(dst, k0) do { \
    _Pragma("unroll") \
    for (int it_ = 0; it_ < 4; ++it_) \
        GLL(W + boffs + (size_t)it_ * 64 * DIMD + (k0), \
            (char*)(dst) + (tid + it_ * 512) * 16); \
} while (0)

    f32x4 acc[8][4];
#pragma unroll
    for (int i = 0; i < 8; i++)
#pragma unroll
        for (int j = 0; j < 4; j++)
            acc[i][j] = f32x4{0.f, 0.f, 0.f, 0.f};

    BT_STAGE_A(&As[0][0], 0);
    BT_STAGE_B(&Bs[0][0], 0);
    asm volatile("" ::: "memory");
    BT_STAGE_A(&As[1][0], KBK);
    asm volatile("s_waitcnt vmcnt(4)" ::: "memory");
    __builtin_amdgcn_s_barrier();

    auto tile = [&](int kt, ushort_t* Asb, ushort_t* Bsb, ushort_t* Bsn) {
        bf16x8 af0[8], af1[8], bf0[4], bf1[4];

        // ---- P0
#pragma unroll
        for (int i = 0; i < 8; i++)
            af0[i] = *(const bf16x8*)(Asb + (wr * 128 + i * 16 + lrow) * KBK + sw0);
#pragma unroll
        for (int j = 0; j < 2; j++)
            bf0[j] = *(const bf16x8*)(Bsb + (wc * 64 + j * 16 + lrow) * KBK + sw0);
        if (kt + 1 < NKT) BT_STAGE_B(Bsn, (kt + 1) * KBK);
        __builtin_amdgcn_s_barrier();
        asm volatile("s_waitcnt lgkmcnt(0)" ::: "memory");
        __builtin_amdgcn_sched_barrier(0);
        __builtin_amdgcn_s_setprio(1);
#pragma unroll
        for (int i = 0; i < 8; i++)
#pragma unroll
            for (int j = 0; j < 2; j++)
                acc[i][j] = __builtin_amdgcn_mfma_f32_16x16x32_bf16(af0[i], bf0[j], acc[i][j], 0, 0, 0);
        __builtin_amdgcn_s_setprio(0);
        __builtin_amdgcn_s_barrier();

        // ---- P1
#pragma unroll
        for (int j = 2; j < 4; j++)
            bf0[j] = *(const bf16x8*)(Bsb + (wc * 64 + j * 16 + lrow) * KBK + sw0);
        __builtin_amdgcn_s_barrier();
        asm volatile("s_waitcnt lgkmcnt(0)" ::: "memory");
        __builtin_amdgcn_sched_barrier(0);
        __builtin_amdgcn_s_setprio(1);
#pragma unroll
        for (int i = 0; i < 8; i++)
#pragma unroll
            for (int j = 2; j < 4; j++)
                acc[i][j] = __builtin_amdgcn_mfma_f32_16x16x32_bf16(af0[i], bf0[j], acc[i][j], 0, 0, 0);
        __builtin_amdgcn_s_setprio(0);
        __builtin_amdgcn_s_barrier();

        // ---- P2
#pragma unroll
        for (int i = 0; i < 8; i++)
            af1[i] = *(const bf16x8*)(Asb + (wr * 128 + i * 16 + lrow) * KBK + sw1);
#pragma unroll
        for (int j = 0; j < 2; j++)
            bf1[j] = *(const bf16x8*)(Bsb + (wc * 64 + j * 16 + lrow) * KBK + sw1);
        __builtin_amdgcn_s_barrier();
        asm volatile("s_waitcnt lgkmcnt(0)" ::: "memory");
        __builtin_amdgcn_sched_barrier(0);
        __builtin_amdgcn_s_setprio(1);
#pragma unroll
        for (int i = 0; i < 8; i++)
#pragma unroll
            for (int j = 0; j < 2; j++)
                acc[i][j] = __builtin_amdgcn_mfma_f32_16x16x32_bf16(af1[i], bf1[j], acc[i][j], 0, 0, 0);
        __builtin_amdgcn_s_setprio(0);
        __builtin_amdgcn_s_barrier();

        // ---- P3
#pragma unroll
        for (int j = 2; j < 4; j++)
            bf1[j] = *(const bf16x8*)(Bsb + (wc * 64 + j * 16 + lrow) * KBK + sw1);
        if (kt + 2 < NKT) BT_STAGE_A(Asb, (kt + 2) * KBK);
        __builtin_amdgcn_s_barrier();
        asm volatile("s_waitcnt lgkmcnt(0)" ::: "memory");
        __builtin_amdgcn_sched_barrier(0);
        __builtin_amdgcn_s_setprio(1);
#pragma unroll
        for (int i = 0; i < 8; i++)
#pragma unroll
            for (int j = 2; j < 4; j++)
                acc[i][j] = __builtin_amdgcn_mfma_f32_16x16x32_bf16(af1[i], bf1[j], acc[i][j], 0, 0, 0);
        __builtin_amdgcn_s_setprio(0);
        if (kt < NKT - 2)       asm volatile("s_waitcnt vmcnt(4)" ::: "memory");
        else if (kt == NKT - 2) asm volatile("s_waitcnt vmcnt(0)" ::: "memory");
        __builtin_amdgcn_s_barrier();
    };

    for (int m = 0; m < NKT / 2; ++m) {
        tile(2 * m,     &As[0][0], &Bs[0][0], &Bs[1][0]);
        tile(2 * m + 1, &As[1][0], &Bs[1][0], &Bs[0][0]);
    }

#pragma unroll
    for (int i = 0; i < 8; i++)
#pragma unroll
        for (int j = 0; j < 4; j++)
#pragma unroll
            for (int r = 0; r < 4; r++) {
                const int row = row0 + wr * 128 + i * 16 + kq * 4 + r;
                const int col = e0 + wc * 64 + j * 16 + lrow;
                Of[(size_t)row * DIMD + col] = acc[i][j][r];
            }
#undef BT_STAGE_A
#undef BT_STAGE_B
}

// ---------------------------------------------------------------------------
// Emit with self-scan: 256-thread blocks, 4 dims/thread (65536 threads).
// Prefix over raw per-chunk sums, FMA order per dim unchanged.
// ---------------------------------------------------------------------------
__global__ __launch_bounds__(256)
void emit(const ushort_t* __restrict__ kvb, const ushort_t* __restrict__ rb,
          const float* __restrict__ td, const float* __restrict__ tf,
          const float* __restrict__ cs, ushort_t* __restrict__ op)
{
    const int t  = blockIdx.x * 256 + threadIdx.x;   // 65536 threads
    const int d0 = (t & 255) * 4;
    const int bc = t >> 8;
    const int c  = bc & (NCHUNK - 1);
    const int b  = bc >> 6;

    float decay[4], eu[4], dL[4], st[4];
#pragma unroll
    for (int j = 0; j < 4; j++) {
        const float w = -__expf(td[d0 + j]);
        decay[j] = __expf(w);
        dL[j]    = __expf(w * (float)CHUNK);
        eu[j]    = __expf(tf[d0 + j]);
        st[j]    = 0.f;
    }

    const float* csb = cs + ((size_t)b * NCHUNK) * DIMD + d0;
    int cp = 0;
    for (; cp + 4 <= c; cp += 4) {
        const float4 s0 = *(const float4*)(csb + (size_t)(cp + 0) * DIMD);
        const float4 s1 = *(const float4*)(csb + (size_t)(cp + 1) * DIMD);
        const float4 s2 = *(const float4*)(csb + (size_t)(cp + 2) * DIMD);
        const float4 s3 = *(const float4*)(csb + (size_t)(cp + 3) * DIMD);
        st[0] = dL[0] * st[0] + s0.x; st[1] = dL[1] * st[1] + s0.y;
        st[2] = dL[2] * st[2] + s0.z; st[3] = dL[3] * st[3] + s0.w;
        st[0] = dL[0] * st[0] + s1.x; st[1] = dL[1] * st[1] + s1.y;
        st[2] = dL[2] * st[2] + s1.z; st[3] = dL[3] * st[3] + s1.w;
        st[0] = dL[0] * st[0] + s2.x; st[1] = dL[1] * st[1] + s2.y;
        st[2] = dL[2] * st[2] + s2.z; st[3] = dL[3] * st[3] + s2.w;
        st[0] = dL[0] * st[0] + s3.x; st[1] = dL[1] * st[1] + s3.y;
        st[2] = dL[2] * st[2] + s3.z; st[3] = dL[3] * st[3] + s3.w;
    }
    for (; cp < c; cp++) {
        const float4 s0 = *(const float4*)(csb + (size_t)cp * DIMD);
        st[0] = dL[0] * st[0] + s0.x; st[1] = dL[1] * st[1] + s0.y;
        st[2] = dL[2] * st[2] + s0.z; st[3] = dL[3] * st[3] + s0.w;
    }

    size_t off = ((size_t)b * SEQ + (size_t)c * CHUNK) * DIMD + d0;
#pragma unroll 8
    for (int i = 0; i < CHUNK; i++) {
        const u16x4 kv4 = *(const u16x4*)(kvb + off);
        const u16x4 r4  = *(const u16x4*)(rb + off);
        u16x4 o4;
#pragma unroll
        for (int j = 0; j < 4; j++) {
            const float kv = b2f(kv4[j]);
            o4[j] = f2b(b2f(r4[j]) * (st[j] + eu[j] * kv));
            st[j] = decay[j] * st[j] + kv;
        }
        *(u16x4*)(op + off) = o4;
        off += DIMD;
    }
}

// ---------------------------------------------------------------------------
// ws: xb/pbuf 32 MiB + weights 8 MiB + cs 1 MiB = 41 MiB.
// d_out (64 MiB f32) doubles as kvb+rb scratch (dead before final GEMM).
// 4 launches: conv_all -> gemm_kvr3 -> emit -> gemm_bt.
// ---------------------------------------------------------------------------
extern "C" void kernel_launch(void* const* d_in, const int* in_sizes, int n_in,
                              void* d_out, int out_size, void* d_ws, size_t ws_size,
                              hipStream_t stream)
{
    const float* x  = (const float*)d_in[0];
    const float* Wk = (const float*)d_in[1];
    const float* Wv = (const float*)d_in[2];
    const float* Wr = (const float*)d_in[3];
    const float* Wo = (const float*)d_in[4];
    const float* td = (const float*)d_in[5];
    const float* tf = (const float*)d_in[6];

    ushort_t* xb  = (ushort_t*)d_ws;                       // 32 MiB; reused as pbuf
    ushort_t* Wb  = xb + (size_t)NTOK * DIMD;              // 8 MiB (4 matrices)
    ushort_t* Wkb = Wb;
    ushort_t* Wvb = Wb + (size_t)DIMD * DIMD;
    ushort_t* Wrb = Wb + 2 * (size_t)DIMD * DIMD;
    ushort_t* Wob = Wb + 3 * (size_t)DIMD * DIMD;
    float*    cs  = (float*)(Wb + 4 * (size_t)DIMD * DIMD); // 1 MiB
    ushort_t* pbuf = xb;

    ushort_t* kvb = (ushort_t*)d_out;                      // 32 MiB scratch
    ushort_t* rb  = kvb + (size_t)NTOK * DIMD;             // 32 MiB scratch
    float*    out = (float*)d_out;

    // 0) all conversions (x + 4 weight matrices), contiguous float4->u16x4
    conv_all<<<(NTOK * (size_t)DIMD / 4 + DIMD * (size_t)DIMD) / 256, 256,
               0, stream>>>(x, Wk, Wv, Wr, Wo, xb, Wb);

    // 1) all three projections in one kernel, A staged once (2 rounds)
    gemm_kvr3<<<dim3(NTOK / 256, DIMD / 128), 512, 0, stream>>>(
        xb, Wkb, Wvb, Wrb, td, kvb, rb, cs);

    // 2) emit (self-scans cs) -> pbuf (xb region)
    emit<<<BATCH * NCHUNK * (DIMD / 4) / 256, 256, 0, stream>>>(
        kvb, rb, td, tf, cs, pbuf);

    // 3) out = out_pre @ Wo^T (f32 epilogue, overwrites d_out)
    gemm_bt<<<dim3(NTOK / 256, DIMD / 256), 512, 0, stream>>>(pbuf, Wob, out);
}

// Round 8
// 291.820 us; speedup vs baseline: 1.0021x; 1.0021x over previous
//
#include <hip/hip_runtime.h>
#include <hip/hip_bf16.h>

// Problem constants
#define DIMD   1024
#define BATCH  4
#define SEQ    4096
#define NTOK   (BATCH * SEQ)   // 16384
#define CHUNK  64              // recurrence chunk length
#define NCHUNK (SEQ / CHUNK)   // 64

// K-tiling for the MFMA GEMMs: 64-deep K tiles, 16 tiles total.
#define KBK    64
#define NKT    (DIMD / KBK)

typedef unsigned short ushort_t;
typedef __attribute__((ext_vector_type(8))) __bf16   bf16x8;
typedef __attribute__((ext_vector_type(4))) float    f32x4;
typedef __attribute__((ext_vector_type(8))) ushort_t u16x8;
typedef __attribute__((ext_vector_type(4))) ushort_t u16x4;

__device__ __forceinline__ float b2f(ushort_t u) {
    union { unsigned int i; float f; } x;
    x.i = ((unsigned int)u) << 16;
    return x.f;
}

__device__ __forceinline__ ushort_t f2b(float f) {
    union { float f; unsigned int i; } x;
    x.f = f;
    unsigned int r = x.i + 0x7fffu + ((x.i >> 16) & 1u);  // RNE
    return (ushort_t)(r >> 16);
}

// 16B global->LDS direct copy. LDS dest must be wave-uniform-base + lane*16
// (linear); swizzling is done on the per-lane GLOBAL source address.
#define GLL(gsrc, ldst) __builtin_amdgcn_global_load_lds( \
    (__attribute__((address_space(1))) void*)(gsrc), \
    (__attribute__((address_space(3))) void*)(ldst), 16, 0, 0)

// ---------------------------------------------------------------------------
// All f32->bf16 conversions in ONE launch, fully contiguous:
// one float4 load -> one u16x4 store per thread. Bit-identical output.
// ---------------------------------------------------------------------------
__global__ __launch_bounds__(256)
void conv_all(const float* __restrict__ x,
              const float* __restrict__ W0, const float* __restrict__ W1,
              const float* __restrict__ W2, const float* __restrict__ W3,
              ushort_t* __restrict__ xb, ushort_t* __restrict__ wb)
{
    const long long i = (long long)blockIdx.x * 256 + threadIdx.x;  // float4 idx
    const long long NX = (long long)NTOK * DIMD / 4;                // 4194304
    const float4* s4;
    ushort_t* dst;
    long long j;
    if (i < NX) {
        s4 = (const float4*)x; j = i; dst = xb;
    } else {
        const long long wj = i - NX;              // < 1048576
        const int m = (int)(wj >> 18);            // 262144 float4 / matrix
        j  = wj & 262143;
        s4 = (const float4*)((m == 0) ? W0 : (m == 1) ? W1 : (m == 2) ? W2 : W3);
        dst = wb + (size_t)m * DIMD * DIMD;
    }
    const float4 a = s4[j];
    u16x4 o;
    o[0] = f2b(a.x); o[1] = f2b(a.y); o[2] = f2b(a.z); o[3] = f2b(a.w);
    *(u16x4*)(dst + j * 4) = o;
}

// ---------------------------------------------------------------------------
// Combined projection launch (best measured: 109.9 us). Blocks 0..511:
// fused k,v GEMM (256x128, kv product + per-chunk sums). Blocks 512..767:
// r projection (256x256 template GEMM with sigmoid epilogue). 512 threads,
// 128 KB LDS, 4-phase counted-vmcnt pipeline, XOR swizzle (global-src +
// read, involution).
// ---------------------------------------------------------------------------
__global__ __launch_bounds__(512, 2)
void gemm_kvrs(const ushort_t* __restrict__ A,
               const ushort_t* __restrict__ Wk,
               const ushort_t* __restrict__ Wv,
               const ushort_t* __restrict__ Wr,
               const float* __restrict__ td,
               ushort_t* __restrict__ Okv,
               ushort_t* __restrict__ Or,
               float* __restrict__ cs)
{
    __shared__ __align__(16) ushort_t smem[65536];   // 128 KB, carved per path

    const int tid  = threadIdx.x;
    const int lane = tid & 63;
    const int wv   = tid >> 6;        // 0..7
    const int lrow = lane & 15;
    const int kq   = lane >> 4;
    const int s8   = lrow & 7;
    const int sw0  = (kq ^ s8) * 8;        // swizzled elem offset, ksub=0
    const int sw1  = ((kq + 4) ^ s8) * 8;  // swizzled elem offset, ksub=1

    // Staging geometry: dest chunk (row, q) <- global (row, q ^ (row&7)).
    const int r_  = tid >> 3;                       // 0..63
    const int q_  = ((tid & 7) ^ (r_ & 7)) * 8;

    if (blockIdx.x < 512) {
        // ================= kv path: block 256 rows x 128 cols ==============
        ushort_t* As0 = smem;                 // 16384 elts each
        ushort_t* As1 = smem + 16384;
        ushort_t* Bk0 = smem + 32768;         // 8192 elts each
        ushort_t* Bk1 = smem + 40960;
        ushort_t* Bv0 = smem + 49152;
        ushort_t* Bv1 = smem + 57344;

        const int wr   = wv >> 1;     // 0..3 : 64-row chunk (= seq chunk)
        const int wc   = wv & 1;      // 0..1 : 64-col half
        const int row0 = (blockIdx.x & 63) * 256;
        const int e0   = (blockIdx.x >> 6) * 128;

        const size_t aoffs = (size_t)(row0 + r_) * DIMD + q_;
        const size_t boffs = (size_t)(e0 + r_) * DIMD + q_;

#define KV_STAGE_A(dst, k0) do { \
    _Pragma("unroll") \
    for (int it_ = 0; it_ < 4; ++it_) \
        GLL(A + aoffs + (size_t)it_ * 64 * DIMD + (k0), \
            (char*)(dst) + (tid + it_ * 512) * 16); \
} while (0)

#define KV_STAGE_B(Wp, dst, k0) do { \
    _Pragma("unroll") \
    for (int it_ = 0; it_ < 2; ++it_) \
        GLL((Wp) + boffs + (size_t)it_ * 64 * DIMD + (k0), \
            (char*)(dst) + (tid + it_ * 512) * 16); \
} while (0)

        f32x4 ak[4][4], av[4][4];
#pragma unroll
        for (int i = 0; i < 4; i++)
#pragma unroll
            for (int j = 0; j < 4; j++) {
                ak[i][j] = f32x4{0.f, 0.f, 0.f, 0.f};
                av[i][j] = f32x4{0.f, 0.f, 0.f, 0.f};
            }

        // Prologue: A0, B0, A1 in flight; drain A0+B0, keep A1 (vmcnt(4)).
        KV_STAGE_A(As0, 0);
        KV_STAGE_B(Wk, Bk0, 0);
        KV_STAGE_B(Wv, Bv0, 0);
        asm volatile("" ::: "memory");
        KV_STAGE_A(As1, KBK);
        asm volatile("s_waitcnt vmcnt(4)" ::: "memory");
        __builtin_amdgcn_s_barrier();

        auto tile = [&](int kt, ushort_t* Asb, ushort_t* Bkb, ushort_t* Bvb,
                        ushort_t* Bkn, ushort_t* Bvn) {
            bf16x8 af0[4], af1[4], b0[4], b1[4], c0[4], c1[4];

            // ---- P0: read A + Bk (ksub0); issue Bk(kt+1); 16 MFMA k-ksub0
#pragma unroll
            for (int i = 0; i < 4; i++)
                af0[i] = *(const bf16x8*)(Asb + (wr * 64 + i * 16 + lrow) * KBK + sw0);
#pragma unroll
            for (int j = 0; j < 4; j++)
                b0[j] = *(const bf16x8*)(Bkb + (wc * 64 + j * 16 + lrow) * KBK + sw0);
            if (kt + 1 < NKT) KV_STAGE_B(Wk, Bkn, (kt + 1) * KBK);
            __builtin_amdgcn_s_barrier();
            asm volatile("s_waitcnt lgkmcnt(0)" ::: "memory");
            __builtin_amdgcn_sched_barrier(0);
            __builtin_amdgcn_s_setprio(1);
#pragma unroll
            for (int i = 0; i < 4; i++)
#pragma unroll
                for (int j = 0; j < 4; j++)
                    ak[i][j] = __builtin_amdgcn_mfma_f32_16x16x32_bf16(af0[i], b0[j], ak[i][j], 0, 0, 0);
            __builtin_amdgcn_s_setprio(0);
            __builtin_amdgcn_s_barrier();

            // ---- P1: read Bv (ksub0); issue Bv(kt+1); 16 MFMA v-ksub0
#pragma unroll
            for (int j = 0; j < 4; j++)
                c0[j] = *(const bf16x8*)(Bvb + (wc * 64 + j * 16 + lrow) * KBK + sw0);
            if (kt + 1 < NKT) KV_STAGE_B(Wv, Bvn, (kt + 1) * KBK);
            __builtin_amdgcn_s_barrier();
            asm volatile("s_waitcnt lgkmcnt(0)" ::: "memory");
            __builtin_amdgcn_sched_barrier(0);
            __builtin_amdgcn_s_setprio(1);
#pragma unroll
            for (int i = 0; i < 4; i++)
#pragma unroll
                for (int j = 0; j < 4; j++)
                    av[i][j] = __builtin_amdgcn_mfma_f32_16x16x32_bf16(af0[i], c0[j], av[i][j], 0, 0, 0);
            __builtin_amdgcn_s_setprio(0);
            __builtin_amdgcn_s_barrier();

            // ---- P2: read A + Bk (ksub1); 16 MFMA k-ksub1
#pragma unroll
            for (int i = 0; i < 4; i++)
                af1[i] = *(const bf16x8*)(Asb + (wr * 64 + i * 16 + lrow) * KBK + sw1);
#pragma unroll
            for (int j = 0; j < 4; j++)
                b1[j] = *(const bf16x8*)(Bkb + (wc * 64 + j * 16 + lrow) * KBK + sw1);
            __builtin_amdgcn_s_barrier();
            asm volatile("s_waitcnt lgkmcnt(0)" ::: "memory");
            __builtin_amdgcn_sched_barrier(0);
            __builtin_amdgcn_s_setprio(1);
#pragma unroll
            for (int i = 0; i < 4; i++)
#pragma unroll
                for (int j = 0; j < 4; j++)
                    ak[i][j] = __builtin_amdgcn_mfma_f32_16x16x32_bf16(af1[i], b1[j], ak[i][j], 0, 0, 0);
            __builtin_amdgcn_s_setprio(0);
            __builtin_amdgcn_s_barrier();

            // ---- P3: read Bv (ksub1); issue A(kt+2) into vacated A buffer
#pragma unroll
            for (int j = 0; j < 4; j++)
                c1[j] = *(const bf16x8*)(Bvb + (wc * 64 + j * 16 + lrow) * KBK + sw1);
            if (kt + 2 < NKT) KV_STAGE_A(Asb, (kt + 2) * KBK);
            __builtin_amdgcn_s_barrier();
            asm volatile("s_waitcnt lgkmcnt(0)" ::: "memory");
            __builtin_amdgcn_sched_barrier(0);
            __builtin_amdgcn_s_setprio(1);
#pragma unroll
            for (int i = 0; i < 4; i++)
#pragma unroll
                for (int j = 0; j < 4; j++)
                    av[i][j] = __builtin_amdgcn_mfma_f32_16x16x32_bf16(af1[i], c1[j], av[i][j], 0, 0, 0);
            __builtin_amdgcn_s_setprio(0);
            // Drain A(kt+1)+B(kt+1); keep A(kt+2) (newest 4) in flight.
            if (kt < NKT - 2)       asm volatile("s_waitcnt vmcnt(4)" ::: "memory");
            else if (kt == NKT - 2) asm volatile("s_waitcnt vmcnt(0)" ::: "memory");
            __builtin_amdgcn_s_barrier();
        };

        for (int m = 0; m < NKT / 2; ++m) {
            tile(2 * m,     As0, Bk0, Bv0, Bk1, Bv1);
            tile(2 * m + 1, As1, Bk1, Bv1, Bk0, Bv0);
        }

        // Epilogue 1: kv store. C/D layout: col = lane&15, row = quad*4+reg.
#pragma unroll
        for (int i = 0; i < 4; i++)
#pragma unroll
            for (int j = 0; j < 4; j++)
#pragma unroll
                for (int r = 0; r < 4; r++) {
                    const int row = row0 + wr * 64 + i * 16 + kq * 4 + r;
                    const int col = e0 + wc * 64 + j * 16 + lrow;
                    Okv[(size_t)row * DIMD + col] = f2b(ak[i][j][r] * av[i][j][r]);
                }

        // Epilogue 2: per-chunk weighted sum s(d) = sum_row decay^(63-row)kv.
#pragma unroll
        for (int j = 0; j < 4; j++) {
            const int col = e0 + wc * 64 + j * 16 + lrow;
            const float w = -__expf(td[col]);
            float s = 0.f;
#pragma unroll
            for (int i = 0; i < 4; i++)
#pragma unroll
                for (int r = 0; r < 4; r++) {
                    const int rl = i * 16 + kq * 4 + r;           // 0..63
                    s += __expf(w * (float)(63 - rl)) * ak[i][j][r] * av[i][j][r];
                }
            s += __shfl_xor(s, 16);
            s += __shfl_xor(s, 32);
            if (kq == 0) {
                const int gchunk = (row0 >> 6) + wr;              // global chunk
                cs[(size_t)gchunk * DIMD + col] = s;
            }
        }
#undef KV_STAGE_A
#undef KV_STAGE_B
    } else {
        // ================= rs path: 256x256 template + sigmoid =============
        ushort_t* As0 = smem;                 // 16384 elts each
        ushort_t* As1 = smem + 16384;
        ushort_t* Bs0 = smem + 32768;
        ushort_t* Bs1 = smem + 49152;

        const int id2  = blockIdx.x - 512;
        const int wr   = wv >> 2;     // 0..1 : 128-row half
        const int wc   = wv & 3;      // 0..3 : 64-col quarter
        const int row0 = (id2 & 63) * 256;
        const int e0   = (id2 >> 6) * 256;

        const size_t aoffs = (size_t)(row0 + r_) * DIMD + q_;
        const size_t boffs = (size_t)(e0 + r_) * DIMD + q_;

#define RS_STAGE_A(dst, k0) do { \
    _Pragma("unroll") \
    for (int it_ = 0; it_ < 4; ++it_) \
        GLL(A + aoffs + (size_t)it_ * 64 * DIMD + (k0), \
            (char*)(dst) + (tid + it_ * 512) * 16); \
} while (0)

#define RS_STAGE_B(dst, k0) do { \
    _Pragma("unroll") \
    for (int it_ = 0; it_ < 4; ++it_) \
        GLL(Wr + boffs + (size_t)it_ * 64 * DIMD + (k0), \
            (char*)(dst) + (tid + it_ * 512) * 16); \
} while (0)

        f32x4 acc[8][4];
#pragma unroll
        for (int i = 0; i < 8; i++)
#pragma unroll
            for (int j = 0; j < 4; j++)
                acc[i][j] = f32x4{0.f, 0.f, 0.f, 0.f};

        RS_STAGE_A(As0, 0);
        RS_STAGE_B(Bs0, 0);
        asm volatile("" ::: "memory");
        RS_STAGE_A(As1, KBK);
        asm volatile("s_waitcnt vmcnt(4)" ::: "memory");
        __builtin_amdgcn_s_barrier();

        auto tile = [&](int kt, ushort_t* Asb, ushort_t* Bsb, ushort_t* Bsn) {
            bf16x8 af0[8], af1[8], bf0[4], bf1[4];

            // ---- P0
#pragma unroll
            for (int i = 0; i < 8; i++)
                af0[i] = *(const bf16x8*)(Asb + (wr * 128 + i * 16 + lrow) * KBK + sw0);
#pragma unroll
            for (int j = 0; j < 2; j++)
                bf0[j] = *(const bf16x8*)(Bsb + (wc * 64 + j * 16 + lrow) * KBK + sw0);
            if (kt + 1 < NKT) RS_STAGE_B(Bsn, (kt + 1) * KBK);
            __builtin_amdgcn_s_barrier();
            asm volatile("s_waitcnt lgkmcnt(0)" ::: "memory");
            __builtin_amdgcn_sched_barrier(0);
            __builtin_amdgcn_s_setprio(1);
#pragma unroll
            for (int i = 0; i < 8; i++)
#pragma unroll
                for (int j = 0; j < 2; j++)
                    acc[i][j] = __builtin_amdgcn_mfma_f32_16x16x32_bf16(af0[i], bf0[j], acc[i][j], 0, 0, 0);
            __builtin_amdgcn_s_setprio(0);
            __builtin_amdgcn_s_barrier();

            // ---- P1
#pragma unroll
            for (int j = 2; j < 4; j++)
                bf0[j] = *(const bf16x8*)(Bsb + (wc * 64 + j * 16 + lrow) * KBK + sw0);
            __builtin_amdgcn_s_barrier();
            asm volatile("s_waitcnt lgkmcnt(0)" ::: "memory");
            __builtin_amdgcn_sched_barrier(0);
            __builtin_amdgcn_s_setprio(1);
#pragma unroll
            for (int i = 0; i < 8; i++)
#pragma unroll
                for (int j = 2; j < 4; j++)
                    acc[i][j] = __builtin_amdgcn_mfma_f32_16x16x32_bf16(af0[i], bf0[j], acc[i][j], 0, 0, 0);
            __builtin_amdgcn_s_setprio(0);
            __builtin_amdgcn_s_barrier();

            // ---- P2
#pragma unroll
            for (int i = 0; i < 8; i++)
                af1[i] = *(const bf16x8*)(Asb + (wr * 128 + i * 16 + lrow) * KBK + sw1);
#pragma unroll
            for (int j = 0; j < 2; j++)
                bf1[j] = *(const bf16x8*)(Bsb + (wc * 64 + j * 16 + lrow) * KBK + sw1);
            __builtin_amdgcn_s_barrier();
            asm volatile("s_waitcnt lgkmcnt(0)" ::: "memory");
            __builtin_amdgcn_sched_barrier(0);
            __builtin_amdgcn_s_setprio(1);
#pragma unroll
            for (int i = 0; i < 8; i++)
#pragma unroll
                for (int j = 0; j < 2; j++)
                    acc[i][j] = __builtin_amdgcn_mfma_f32_16x16x32_bf16(af1[i], bf1[j], acc[i][j], 0, 0, 0);
            __builtin_amdgcn_s_setprio(0);
            __builtin_amdgcn_s_barrier();

            // ---- P3
#pragma unroll
            for (int j = 2; j < 4; j++)
                bf1[j] = *(const bf16x8*)(Bsb + (wc * 64 + j * 16 + lrow) * KBK + sw1);
            if (kt + 2 < NKT) RS_STAGE_A(Asb, (kt + 2) * KBK);
            __builtin_amdgcn_s_barrier();
            asm volatile("s_waitcnt lgkmcnt(0)" ::: "memory");
            __builtin_amdgcn_sched_barrier(0);
            __builtin_amdgcn_s_setprio(1);
#pragma unroll
            for (int i = 0; i < 8; i++)
#pragma unroll
                for (int j = 2; j < 4; j++)
                    acc[i][j] = __builtin_amdgcn_mfma_f32_16x16x32_bf16(af1[i], bf1[j], acc[i][j], 0, 0, 0);
            __builtin_amdgcn_s_setprio(0);
            if (kt < NKT - 2)       asm volatile("s_waitcnt vmcnt(4)" ::: "memory");
            else if (kt == NKT - 2) asm volatile("s_waitcnt vmcnt(0)" ::: "memory");
            __builtin_amdgcn_s_barrier();
        };

        for (int m = 0; m < NKT / 2; ++m) {
            tile(2 * m,     As0, Bs0, Bs1);
            tile(2 * m + 1, As1, Bs1, Bs0);
        }

#pragma unroll
        for (int i = 0; i < 8; i++)
#pragma unroll
            for (int j = 0; j < 4; j++)
#pragma unroll
                for (int r = 0; r < 4; r++) {
                    const int row = row0 + wr * 128 + i * 16 + kq * 4 + r;
                    const int col = e0 + wc * 64 + j * 16 + lrow;
                    Or[(size_t)row * DIMD + col] =
                        f2b(1.f / (1.f + __expf(-acc[i][j][r])));
                }
#undef RS_STAGE_A
#undef RS_STAGE_B
    }
}

// ---------------------------------------------------------------------------
// Final GEMM: C[n,e] = sum_d A[n,d] * W[e,d], f32 out.
// 256x256 block, 512 threads, 4-phase counted-vmcnt pipeline + swizzle.
// ---------------------------------------------------------------------------
__global__ __launch_bounds__(512, 2)
void gemm_bt(const ushort_t* __restrict__ A,
             const ushort_t* __restrict__ W,
             float* __restrict__ Of)
{
    __shared__ __align__(16) ushort_t As[2][256 * KBK];  // 2 x 32 KB
    __shared__ __align__(16) ushort_t Bs[2][256 * KBK];  // 2 x 32 KB

    const int tid  = threadIdx.x;
    const int lane = tid & 63;
    const int wv   = tid >> 6;
    const int wr   = wv >> 2;
    const int wc   = wv & 3;
    const int lrow = lane & 15;
    const int kq   = lane >> 4;
    const int s8   = lrow & 7;
    const int sw0  = (kq ^ s8) * 8;
    const int sw1  = ((kq + 4) ^ s8) * 8;

    const int row0 = blockIdx.x * 256;
    const int e0   = blockIdx.y * 256;

    const int r_  = tid >> 3;
    const int q_  = ((tid & 7) ^ (r_ & 7)) * 8;
    const size_t aoffs = (size_t)(row0 + r_) * DIMD + q_;
    const size_t boffs = (size_t)(e0 + r_) * DIMD + q_;

#define BT_STAGE_A(dst, k0) do { \
    _Pragma("unroll") \
    for (int it_ = 0; it_ < 4; ++it_) \
        GLL(A + aoffs + (size_t)it_ * 64 * DIMD + (k0), \
            (char*)(dst) + (tid + it_ * 512) * 16); \
} while (0)

#define BT_STAGE_B(dst, k0) do { \
    _Pragma("unroll") \
    for (int it_ = 0; it_ < 4; ++it_) \
        GLL(W + boffs + (size_t)it_ * 64 * DIMD + (k0), \
            (char*)(dst) + (tid + it_ * 512) * 16); \
} while (0)

    f32x4 acc[8][4];
#pragma unroll
    for (int i = 0; i < 8; i++)
#pragma unroll
        for (int j = 0; j < 4; j++)
            acc[i][j] = f32x4{0.f, 0.f, 0.f, 0.f};

    BT_STAGE_A(&As[0][0], 0);
    BT_STAGE_B(&Bs[0][0], 0);
    asm volatile("" ::: "memory");
    BT_STAGE_A(&As[1][0], KBK);
    asm volatile("s_waitcnt vmcnt(4)" ::: "memory");
    __builtin_amdgcn_s_barrier();

    auto tile = [&](int kt, ushort_t* Asb, ushort_t* Bsb, ushort_t* Bsn) {
        bf16x8 af0[8], af1[8], bf0[4], bf1[4];

        // ---- P0
#pragma unroll
        for (int i = 0; i < 8; i++)
            af0[i] = *(const bf16x8*)(Asb + (wr * 128 + i * 16 + lrow) * KBK + sw0);
#pragma unroll
        for (int j = 0; j < 2; j++)
            bf0[j] = *(const bf16x8*)(Bsb + (wc * 64 + j * 16 + lrow) * KBK + sw0);
        if (kt + 1 < NKT) BT_STAGE_B(Bsn, (kt + 1) * KBK);
        __builtin_amdgcn_s_barrier();
        asm volatile("s_waitcnt lgkmcnt(0)" ::: "memory");
        __builtin_amdgcn_sched_barrier(0);
        __builtin_amdgcn_s_setprio(1);
#pragma unroll
        for (int i = 0; i < 8; i++)
#pragma unroll
            for (int j = 0; j < 2; j++)
                acc[i][j] = __builtin_amdgcn_mfma_f32_16x16x32_bf16(af0[i], bf0[j], acc[i][j], 0, 0, 0);
        __builtin_amdgcn_s_setprio(0);
        __builtin_amdgcn_s_barrier();

        // ---- P1
#pragma unroll
        for (int j = 2; j < 4; j++)
            bf0[j] = *(const bf16x8*)(Bsb + (wc * 64 + j * 16 + lrow) * KBK + sw0);
        __builtin_amdgcn_s_barrier();
        asm volatile("s_waitcnt lgkmcnt(0)" ::: "memory");
        __builtin_amdgcn_sched_barrier(0);
        __builtin_amdgcn_s_setprio(1);
#pragma unroll
        for (int i = 0; i < 8; i++)
#pragma unroll
            for (int j = 2; j < 4; j++)
                acc[i][j] = __builtin_amdgcn_mfma_f32_16x16x32_bf16(af0[i], bf0[j], acc[i][j], 0, 0, 0);
        __builtin_amdgcn_s_setprio(0);
        __builtin_amdgcn_s_barrier();

        // ---- P2
#pragma unroll
        for (int i = 0; i < 8; i++)
            af1[i] = *(const bf16x8*)(Asb + (wr * 128 + i * 16 + lrow) * KBK + sw1);
#pragma unroll
        for (int j = 0; j < 2; j++)
            bf1[j] = *(const bf16x8*)(Bsb + (wc * 64 + j * 16 + lrow) * KBK + sw1);
        __builtin_amdgcn_s_barrier();
        asm volatile("s_waitcnt lgkmcnt(0)" ::: "memory");
        __builtin_amdgcn_sched_barrier(0);
        __builtin_amdgcn_s_setprio(1);
#pragma unroll
        for (int i = 0; i < 8; i++)
#pragma unroll
            for (int j = 0; j < 2; j++)
                acc[i][j] = __builtin_amdgcn_mfma_f32_16x16x32_bf16(af1[i], bf1[j], acc[i][j], 0, 0, 0);
        __builtin_amdgcn_s_setprio(0);
        __builtin_amdgcn_s_barrier();

        // ---- P3
#pragma unroll
        for (int j = 2; j < 4; j++)
            bf1[j] = *(const bf16x8*)(Bsb + (wc * 64 + j * 16 + lrow) * KBK + sw1);
        if (kt + 2 < NKT) BT_STAGE_A(Asb, (kt + 2) * KBK);
        __builtin_amdgcn_s_barrier();
        asm volatile("s_waitcnt lgkmcnt(0)" ::: "memory");
        __builtin_amdgcn_sched_barrier(0);
        __builtin_amdgcn_s_setprio(1);
#pragma unroll
        for (int i = 0; i < 8; i++)
#pragma unroll
            for (int j = 2; j < 4; j++)
                acc[i][j] = __builtin_amdgcn_mfma_f32_16x16x32_bf16(af1[i], bf1[j], acc[i][j], 0, 0, 0);
        __builtin_amdgcn_s_setprio(0);
        if (kt < NKT - 2)       asm volatile("s_waitcnt vmcnt(4)" ::: "memory");
        else if (kt == NKT - 2) asm volatile("s_waitcnt vmcnt(0)" ::: "memory");
        __builtin_amdgcn_s_barrier();
    };

    for (int m = 0; m < NKT / 2; ++m) {
        tile(2 * m,     &As[0][0], &Bs[0][0], &Bs[1][0]);
        tile(2 * m + 1, &As[1][0], &Bs[1][0], &Bs[0][0]);
    }

#pragma unroll
    for (int i = 0; i < 8; i++)
#pragma unroll
        for (int j = 0; j < 4; j++)
#pragma unroll
            for (int r = 0; r < 4; r++) {
                const int row = row0 + wr * 128 + i * 16 + kq * 4 + r;
                const int col = e0 + wc * 64 + j * 16 + lrow;
                Of[(size_t)row * DIMD + col] = acc[i][j][r];
            }
#undef BT_STAGE_A
#undef BT_STAGE_B
}

// ---------------------------------------------------------------------------
// Emit with self-scan: 256-thread blocks, 4 dims/thread (65536 threads).
// Prefix over raw per-chunk sums, FMA order per dim unchanged.
// ---------------------------------------------------------------------------
__global__ __launch_bounds__(256)
void emit(const ushort_t* __restrict__ kvb, const ushort_t* __restrict__ rb,
          const float* __restrict__ td, const float* __restrict__ tf,
          const float* __restrict__ cs, ushort_t* __restrict__ op)
{
    const int t  = blockIdx.x * 256 + threadIdx.x;   // 65536 threads
    const int d0 = (t & 255) * 4;
    const int bc = t >> 8;
    const int c  = bc & (NCHUNK - 1);
    const int b  = bc >> 6;

    float decay[4], eu[4], dL[4], st[4];
#pragma unroll
    for (int j = 0; j < 4; j++) {
        const float w = -__expf(td[d0 + j]);
        decay[j] = __expf(w);
        dL[j]    = __expf(w * (float)CHUNK);
        eu[j]    = __expf(tf[d0 + j]);
        st[j]    = 0.f;
    }

    const float* csb = cs + ((size_t)b * NCHUNK) * DIMD + d0;
    int cp = 0;
    for (; cp + 4 <= c; cp += 4) {
        const float4 s0 = *(const float4*)(csb + (size_t)(cp + 0) * DIMD);
        const float4 s1 = *(const float4*)(csb + (size_t)(cp + 1) * DIMD);
        const float4 s2 = *(const float4*)(csb + (size_t)(cp + 2) * DIMD);
        const float4 s3 = *(const float4*)(csb + (size_t)(cp + 3) * DIMD);
        st[0] = dL[0] * st[0] + s0.x; st[1] = dL[1] * st[1] + s0.y;
        st[2] = dL[2] * st[2] + s0.z; st[3] = dL[3] * st[3] + s0.w;
        st[0] = dL[0] * st[0] + s1.x; st[1] = dL[1] * st[1] + s1.y;
        st[2] = dL[2] * st[2] + s1.z; st[3] = dL[3] * st[3] + s1.w;
        st[0] = dL[0] * st[0] + s2.x; st[1] = dL[1] * st[1] + s2.y;
        st[2] = dL[2] * st[2] + s2.z; st[3] = dL[3] * st[3] + s2.w;
        st[0] = dL[0] * st[0] + s3.x; st[1] = dL[1] * st[1] + s3.y;
        st[2] = dL[2] * st[2] + s3.z; st[3] = dL[3] * st[3] + s3.w;
    }
    for (; cp < c; cp++) {
        const float4 s0 = *(const float4*)(csb + (size_t)cp * DIMD);
        st[0] = dL[0] * st[0] + s0.x; st[1] = dL[1] * st[1] + s0.y;
        st[2] = dL[2] * st[2] + s0.z; st[3] = dL[3] * st[3] + s0.w;
    }

    size_t off = ((size_t)b * SEQ + (size_t)c * CHUNK) * DIMD + d0;
#pragma unroll 8
    for (int i = 0; i < CHUNK; i++) {
        const u16x4 kv4 = *(const u16x4*)(kvb + off);
        const u16x4 r4  = *(const u16x4*)(rb + off);
        u16x4 o4;
#pragma unroll
        for (int j = 0; j < 4; j++) {
            const float kv = b2f(kv4[j]);
            o4[j] = f2b(b2f(r4[j]) * (st[j] + eu[j] * kv));
            st[j] = decay[j] * st[j] + kv;
        }
        *(u16x4*)(op + off) = o4;
        off += DIMD;
    }
}

// ---------------------------------------------------------------------------
// ws: xb/pbuf 32 MiB + weights 8 MiB + cs 1 MiB = 41 MiB.
// d_out (64 MiB f32) doubles as kvb+rb scratch (dead before final GEMM).
// 4 launches: conv_all -> gemm_kvrs -> emit -> gemm_bt.
// ---------------------------------------------------------------------------
extern "C" void kernel_launch(void* const* d_in, const int* in_sizes, int n_in,
                              void* d_out, int out_size, void* d_ws, size_t ws_size,
                              hipStream_t stream)
{
    const float* x  = (const float*)d_in[0];
    const float* Wk = (const float*)d_in[1];
    const float* Wv = (const float*)d_in[2];
    const float* Wr = (const float*)d_in[3];
    const float* Wo = (const float*)d_in[4];
    const float* td = (const float*)d_in[5];
    const float* tf = (const float*)d_in[6];

    ushort_t* xb  = (ushort_t*)d_ws;                       // 32 MiB; reused as pbuf
    ushort_t* Wb  = xb + (size_t)NTOK * DIMD;              // 8 MiB (4 matrices)
    ushort_t* Wkb = Wb;
    ushort_t* Wvb = Wb + (size_t)DIMD * DIMD;
    ushort_t* Wrb = Wb + 2 * (size_t)DIMD * DIMD;
    ushort_t* Wob = Wb + 3 * (size_t)DIMD * DIMD;
    float*    cs  = (float*)(Wb + 4 * (size_t)DIMD * DIMD); // 1 MiB
    ushort_t* pbuf = xb;

    ushort_t* kvb = (ushort_t*)d_out;                      // 32 MiB scratch
    ushort_t* rb  = kvb + (size_t)NTOK * DIMD;             // 32 MiB scratch
    float*    out = (float*)d_out;

    // 0) all conversions (x + 4 weight matrices), contiguous float4->u16x4
    conv_all<<<(NTOK * (size_t)DIMD / 4 + DIMD * (size_t)DIMD) / 256, 256,
               0, stream>>>(x, Wk, Wv, Wr, Wo, xb, Wb);

    // 1) kv projection (+ per-chunk aggregates) and r projection, one launch
    gemm_kvrs<<<512 + 256, 512, 0, stream>>>(
        xb, Wkb, Wvb, Wrb, td, kvb, rb, cs);

    // 2) emit (self-scans cs) -> pbuf (xb region)
    emit<<<BATCH * NCHUNK * (DIMD / 4) / 256, 256, 0, stream>>>(
        kvb, rb, td, tf, cs, pbuf);

    // 3) out = out_pre @ Wo^T (f32 epilogue, overwrites d_out)
    gemm_bt<<<dim3(NTOK / 256, DIMD / 256), 512, 0, stream>>>(pbuf, Wob, out);
}

// Round 10
// 279.327 us; speedup vs baseline: 1.0469x; 1.0447x over previous
//
#include <hip/hip_runtime.h>
#include <hip/hip_bf16.h>

// Problem constants
#define DIMD   1024
#define BATCH  4
#define SEQ    4096
#define NTOK   (BATCH * SEQ)   // 16384
#define CHUNK  64              // recurrence chunk length
#define NCHUNK (SEQ / CHUNK)   // 64

// K-tiling for the MFMA GEMMs: 64-deep K tiles, 16 tiles total.
#define KBK    64
#define NKT    (DIMD / KBK)

typedef unsigned short ushort_t;
typedef __attribute__((ext_vector_type(8))) __bf16   bf16x8;
typedef __attribute__((ext_vector_type(4))) float    f32x4;
typedef __attribute__((ext_vector_type(8))) ushort_t u16x8;
typedef __attribute__((ext_vector_type(4))) ushort_t u16x4;

__device__ __forceinline__ float b2f(ushort_t u) {
    union { unsigned int i; float f; } x;
    x.i = ((unsigned int)u) << 16;
    return x.f;
}

__device__ __forceinline__ ushort_t f2b(float f) {
    union { float f; unsigned int i; } x;
    x.f = f;
    unsigned int r = x.i + 0x7fffu + ((x.i >> 16) & 1u);  // RNE
    return (ushort_t)(r >> 16);
}

// 16B global->LDS direct copy. LDS dest must be wave-uniform-base + lane*16
// (linear); swizzling is done on the per-lane GLOBAL source address.
#define GLL(gsrc, ldst) __builtin_amdgcn_global_load_lds( \
    (__attribute__((address_space(1))) void*)(gsrc), \
    (__attribute__((address_space(3))) void*)(ldst), 16, 0, 0)

// ---------------------------------------------------------------------------
// All f32->bf16 conversions in ONE launch, fully contiguous:
// one float4 load -> one u16x4 store per thread. Bit-identical output.
// ---------------------------------------------------------------------------
__global__ __launch_bounds__(256)
void conv_all(const float* __restrict__ x,
              const float* __restrict__ W0, const float* __restrict__ W1,
              const float* __restrict__ W2, const float* __restrict__ W3,
              ushort_t* __restrict__ xb, ushort_t* __restrict__ wb)
{
    const long long i = (long long)blockIdx.x * 256 + threadIdx.x;  // float4 idx
    const long long NX = (long long)NTOK * DIMD / 4;                // 4194304
    const float4* s4;
    ushort_t* dst;
    long long j;
    if (i < NX) {
        s4 = (const float4*)x; j = i; dst = xb;
    } else {
        const long long wj = i - NX;              // < 1048576
        const int m = (int)(wj >> 18);            // 262144 float4 / matrix
        j  = wj & 262143;
        s4 = (const float4*)((m == 0) ? W0 : (m == 1) ? W1 : (m == 2) ? W2 : W3);
        dst = wb + (size_t)m * DIMD * DIMD;
    }
    const float4 a = s4[j];
    u16x4 o;
    o[0] = f2b(a.x); o[1] = f2b(a.y); o[2] = f2b(a.z); o[3] = f2b(a.w);
    *(u16x4*)(dst + j * 4) = o;
}

// ---------------------------------------------------------------------------
// Combined projection launch. Blocks 0..511: fused k,v GEMM (256x128, kv
// product + per-chunk sums). Blocks 512..767: r projection (256x256 with
// sigmoid epilogue). 512 threads, 128 KB LDS, 4-phase counted-vmcnt
// pipeline, XOR swizzle (global-src + read, involution).
// R9 change: sched_barrier(0) pins removed — compiler now emits fine-grained
// lgkmcnt between ds_reads and MFMAs (rule 18 applies only to inline-asm
// ds_reads; the asm lgkmcnt(0)+"memory" still orders all memory ops, so the
// stage-into-read-buffer guards remain intact).
// ---------------------------------------------------------------------------
__global__ __launch_bounds__(512, 2)
void gemm_kvrs(const ushort_t* __restrict__ A,
               const ushort_t* __restrict__ Wk,
               const ushort_t* __restrict__ Wv,
               const ushort_t* __restrict__ Wr,
               const float* __restrict__ td,
               ushort_t* __restrict__ Okv,
               ushort_t* __restrict__ Or,
               float* __restrict__ cs)
{
    __shared__ __align__(16) ushort_t smem[65536];   // 128 KB, carved per path

    const int tid  = threadIdx.x;
    const int lane = tid & 63;
    const int wv   = tid >> 6;        // 0..7
    const int lrow = lane & 15;
    const int kq   = lane >> 4;
    const int s8   = lrow & 7;
    const int sw0  = (kq ^ s8) * 8;        // swizzled elem offset, ksub=0
    const int sw1  = ((kq + 4) ^ s8) * 8;  // swizzled elem offset, ksub=1

    // Staging geometry: dest chunk (row, q) <- global (row, q ^ (row&7)).
    const int r_  = tid >> 3;                       // 0..63
    const int q_  = ((tid & 7) ^ (r_ & 7)) * 8;

    if (blockIdx.x < 512) {
        // ================= kv path: block 256 rows x 128 cols ==============
        ushort_t* As0 = smem;                 // 16384 elts each
        ushort_t* As1 = smem + 16384;
        ushort_t* Bk0 = smem + 32768;         // 8192 elts each
        ushort_t* Bk1 = smem + 40960;
        ushort_t* Bv0 = smem + 49152;
        ushort_t* Bv1 = smem + 57344;

        const int wr   = wv >> 1;     // 0..3 : 64-row chunk (= seq chunk)
        const int wc   = wv & 1;      // 0..1 : 64-col half
        const int row0 = (blockIdx.x & 63) * 256;
        const int e0   = (blockIdx.x >> 6) * 128;

        const size_t aoffs = (size_t)(row0 + r_) * DIMD + q_;
        const size_t boffs = (size_t)(e0 + r_) * DIMD + q_;

#define KV_STAGE_A(dst, k0) do { \
    _Pragma("unroll") \
    for (int it_ = 0; it_ < 4; ++it_) \
        GLL(A + aoffs + (size_t)it_ * 64 * DIMD + (k0), \
            (char*)(dst) + (tid + it_ * 512) * 16); \
} while (0)

#define KV_STAGE_B(Wp, dst, k0) do { \
    _Pragma("unroll") \
    for (int it_ = 0; it_ < 2; ++it_) \
        GLL((Wp) + boffs + (size_t)it_ * 64 * DIMD + (k0), \
            (char*)(dst) + (tid + it_ * 512) * 16); \
} while (0)

        f32x4 ak[4][4], av[4][4];
#pragma unroll
        for (int i = 0; i < 4; i++)
#pragma unroll
            for (int j = 0; j < 4; j++) {
                ak[i][j] = f32x4{0.f, 0.f, 0.f, 0.f};
                av[i][j] = f32x4{0.f, 0.f, 0.f, 0.f};
            }

        // Prologue: A0, B0, A1 in flight; drain A0+B0, keep A1 (vmcnt(4)).
        KV_STAGE_A(As0, 0);
        KV_STAGE_B(Wk, Bk0, 0);
        KV_STAGE_B(Wv, Bv0, 0);
        asm volatile("" ::: "memory");
        KV_STAGE_A(As1, KBK);
        asm volatile("s_waitcnt vmcnt(4)" ::: "memory");
        __builtin_amdgcn_s_barrier();

        auto tile = [&](int kt, ushort_t* Asb, ushort_t* Bkb, ushort_t* Bvb,
                        ushort_t* Bkn, ushort_t* Bvn) {
            bf16x8 af0[4], af1[4], b0[4], b1[4], c0[4], c1[4];

            // ---- P0: read A + Bk (ksub0); issue Bk(kt+1); 16 MFMA k-ksub0
#pragma unroll
            for (int i = 0; i < 4; i++)
                af0[i] = *(const bf16x8*)(Asb + (wr * 64 + i * 16 + lrow) * KBK + sw0);
#pragma unroll
            for (int j = 0; j < 4; j++)
                b0[j] = *(const bf16x8*)(Bkb + (wc * 64 + j * 16 + lrow) * KBK + sw0);
            if (kt + 1 < NKT) KV_STAGE_B(Wk, Bkn, (kt + 1) * KBK);
            __builtin_amdgcn_s_barrier();
            asm volatile("s_waitcnt lgkmcnt(0)" ::: "memory");
            __builtin_amdgcn_s_setprio(1);
#pragma unroll
            for (int i = 0; i < 4; i++)
#pragma unroll
                for (int j = 0; j < 4; j++)
                    ak[i][j] = __builtin_amdgcn_mfma_f32_16x16x32_bf16(af0[i], b0[j], ak[i][j], 0, 0, 0);
            __builtin_amdgcn_s_setprio(0);
            __builtin_amdgcn_s_barrier();

            // ---- P1: read Bv (ksub0); issue Bv(kt+1); 16 MFMA v-ksub0
#pragma unroll
            for (int j = 0; j < 4; j++)
                c0[j] = *(const bf16x8*)(Bvb + (wc * 64 + j * 16 + lrow) * KBK + sw0);
            if (kt + 1 < NKT) KV_STAGE_B(Wv, Bvn, (kt + 1) * KBK);
            __builtin_amdgcn_s_barrier();
            asm volatile("s_waitcnt lgkmcnt(0)" ::: "memory");
            __builtin_amdgcn_s_setprio(1);
#pragma unroll
            for (int i = 0; i < 4; i++)
#pragma unroll
                for (int j = 0; j < 4; j++)
                    av[i][j] = __builtin_amdgcn_mfma_f32_16x16x32_bf16(af0[i], c0[j], av[i][j], 0, 0, 0);
            __builtin_amdgcn_s_setprio(0);
            __builtin_amdgcn_s_barrier();

            // ---- P2: read A + Bk (ksub1); 16 MFMA k-ksub1
#pragma unroll
            for (int i = 0; i < 4; i++)
                af1[i] = *(const bf16x8*)(Asb + (wr * 64 + i * 16 + lrow) * KBK + sw1);
#pragma unroll
            for (int j = 0; j < 4; j++)
                b1[j] = *(const bf16x8*)(Bkb + (wc * 64 + j * 16 + lrow) * KBK + sw1);
            __builtin_amdgcn_s_barrier();
            asm volatile("s_waitcnt lgkmcnt(0)" ::: "memory");
            __builtin_amdgcn_s_setprio(1);
#pragma unroll
            for (int i = 0; i < 4; i++)
#pragma unroll
                for (int j = 0; j < 4; j++)
                    ak[i][j] = __builtin_amdgcn_mfma_f32_16x16x32_bf16(af1[i], b1[j], ak[i][j], 0, 0, 0);
            __builtin_amdgcn_s_setprio(0);
            __builtin_amdgcn_s_barrier();

            // ---- P3: read Bv (ksub1); issue A(kt+2) into vacated A buffer
            //      (all A reads drained at P2's lgkm+barrier -> safe)
#pragma unroll
            for (int j = 0; j < 4; j++)
                c1[j] = *(const bf16x8*)(Bvb + (wc * 64 + j * 16 + lrow) * KBK + sw1);
            if (kt + 2 < NKT) KV_STAGE_A(Asb, (kt + 2) * KBK);
            __builtin_amdgcn_s_barrier();
            asm volatile("s_waitcnt lgkmcnt(0)" ::: "memory");
            __builtin_amdgcn_s_setprio(1);
#pragma unroll
            for (int i = 0; i < 4; i++)
#pragma unroll
                for (int j = 0; j < 4; j++)
                    av[i][j] = __builtin_amdgcn_mfma_f32_16x16x32_bf16(af1[i], c1[j], av[i][j], 0, 0, 0);
            __builtin_amdgcn_s_setprio(0);
            // Drain A(kt+1)+B(kt+1); keep A(kt+2) (newest 4) in flight.
            if (kt < NKT - 2)       asm volatile("s_waitcnt vmcnt(4)" ::: "memory");
            else if (kt == NKT - 2) asm volatile("s_waitcnt vmcnt(0)" ::: "memory");
            __builtin_amdgcn_s_barrier();
        };

        for (int m = 0; m < NKT / 2; ++m) {
            tile(2 * m,     As0, Bk0, Bv0, Bk1, Bv1);
            tile(2 * m + 1, As1, Bk1, Bv1, Bk0, Bv0);
        }

        // Epilogue 1: kv store. C/D layout: col = lane&15, row = quad*4+reg.
#pragma unroll
        for (int i = 0; i < 4; i++)
#pragma unroll
            for (int j = 0; j < 4; j++)
#pragma unroll
                for (int r = 0; r < 4; r++) {
                    const int row = row0 + wr * 64 + i * 16 + kq * 4 + r;
                    const int col = e0 + wc * 64 + j * 16 + lrow;
                    Okv[(size_t)row * DIMD + col] = f2b(ak[i][j][r] * av[i][j][r]);
                }

        // Epilogue 2: per-chunk weighted sum s(d) = sum_row decay^(63-row)kv.
#pragma unroll
        for (int j = 0; j < 4; j++) {
            const int col = e0 + wc * 64 + j * 16 + lrow;
            const float w = -__expf(td[col]);
            float s = 0.f;
#pragma unroll
            for (int i = 0; i < 4; i++)
#pragma unroll
                for (int r = 0; r < 4; r++) {
                    const int rl = i * 16 + kq * 4 + r;           // 0..63
                    s += __expf(w * (float)(63 - rl)) * ak[i][j][r] * av[i][j][r];
                }
            s += __shfl_xor(s, 16);
            s += __shfl_xor(s, 32);
            if (kq == 0) {
                const int gchunk = (row0 >> 6) + wr;              // global chunk
                cs[(size_t)gchunk * DIMD + col] = s;
            }
        }
#undef KV_STAGE_A
#undef KV_STAGE_B
    } else {
        // ================= rs path: 256x256 template + sigmoid =============
        ushort_t* As0 = smem;                 // 16384 elts each
        ushort_t* As1 = smem + 16384;
        ushort_t* Bs0 = smem + 32768;
        ushort_t* Bs1 = smem + 49152;

        const int id2  = blockIdx.x - 512;
        const int wr   = wv >> 2;     // 0..1 : 128-row half
        const int wc   = wv & 3;      // 0..3 : 64-col quarter
        const int row0 = (id2 & 63) * 256;
        const int e0   = (id2 >> 6) * 256;

        const size_t aoffs = (size_t)(row0 + r_) * DIMD + q_;
        const size_t boffs = (size_t)(e0 + r_) * DIMD + q_;

#define RS_STAGE_A(dst, k0) do { \
    _Pragma("unroll") \
    for (int it_ = 0; it_ < 4; ++it_) \
        GLL(A + aoffs + (size_t)it_ * 64 * DIMD + (k0), \
            (char*)(dst) + (tid + it_ * 512) * 16); \
} while (0)

#define RS_STAGE_B(dst, k0) do { \
    _Pragma("unroll") \
    for (int it_ = 0; it_ < 4; ++it_) \
        GLL(Wr + boffs + (size_t)it_ * 64 * DIMD + (k0), \
            (char*)(dst) + (tid + it_ * 512) * 16); \
} while (0)

        f32x4 acc[8][4];
#pragma unroll
        for (int i = 0; i < 8; i++)
#pragma unroll
            for (int j = 0; j < 4; j++)
                acc[i][j] = f32x4{0.f, 0.f, 0.f, 0.f};

        RS_STAGE_A(As0, 0);
        RS_STAGE_B(Bs0, 0);
        asm volatile("" ::: "memory");
        RS_STAGE_A(As1, KBK);
        asm volatile("s_waitcnt vmcnt(4)" ::: "memory");
        __builtin_amdgcn_s_barrier();

        auto tile = [&](int kt, ushort_t* Asb, ushort_t* Bsb, ushort_t* Bsn) {
            bf16x8 af0[8], af1[8], bf0[4], bf1[4];

            // ---- P0
#pragma unroll
            for (int i = 0; i < 8; i++)
                af0[i] = *(const bf16x8*)(Asb + (wr * 128 + i * 16 + lrow) * KBK + sw0);
#pragma unroll
            for (int j = 0; j < 2; j++)
                bf0[j] = *(const bf16x8*)(Bsb + (wc * 64 + j * 16 + lrow) * KBK + sw0);
            if (kt + 1 < NKT) RS_STAGE_B(Bsn, (kt + 1) * KBK);
            __builtin_amdgcn_s_barrier();
            asm volatile("s_waitcnt lgkmcnt(0)" ::: "memory");
            __builtin_amdgcn_s_setprio(1);
#pragma unroll
            for (int i = 0; i < 8; i++)
#pragma unroll
                for (int j = 0; j < 2; j++)
                    acc[i][j] = __builtin_amdgcn_mfma_f32_16x16x32_bf16(af0[i], bf0[j], acc[i][j], 0, 0, 0);
            __builtin_amdgcn_s_setprio(0);
            __builtin_amdgcn_s_barrier();

            // ---- P1
#pragma unroll
            for (int j = 2; j < 4; j++)
                bf0[j] = *(const bf16x8*)(Bsb + (wc * 64 + j * 16 + lrow) * KBK + sw0);
            __builtin_amdgcn_s_barrier();
            asm volatile("s_waitcnt lgkmcnt(0)" ::: "memory");
            __builtin_amdgcn_s_setprio(1);
#pragma unroll
            for (int i = 0; i < 8; i++)
#pragma unroll
                for (int j = 2; j < 4; j++)
                    acc[i][j] = __builtin_amdgcn_mfma_f32_16x16x32_bf16(af0[i], bf0[j], acc[i][j], 0, 0, 0);
            __builtin_amdgcn_s_setprio(0);
            __builtin_amdgcn_s_barrier();

            // ---- P2
#pragma unroll
            for (int i = 0; i < 8; i++)
                af1[i] = *(const bf16x8*)(Asb + (wr * 128 + i * 16 + lrow) * KBK + sw1);
#pragma unroll
            for (int j = 0; j < 2; j++)
                bf1[j] = *(const bf16x8*)(Bsb + (wc * 64 + j * 16 + lrow) * KBK + sw1);
            __builtin_amdgcn_s_barrier();
            asm volatile("s_waitcnt lgkmcnt(0)" ::: "memory");
            __builtin_amdgcn_s_setprio(1);
#pragma unroll
            for (int i = 0; i < 8; i++)
#pragma unroll
                for (int j = 0; j < 2; j++)
                    acc[i][j] = __builtin_amdgcn_mfma_f32_16x16x32_bf16(af1[i], bf1[j], acc[i][j], 0, 0, 0);
            __builtin_amdgcn_s_setprio(0);
            __builtin_amdgcn_s_barrier();

            // ---- P3
#pragma unroll
            for (int j = 2; j < 4; j++)
                bf1[j] = *(const bf16x8*)(Bsb + (wc * 64 + j * 16 + lrow) * KBK + sw1);
            if (kt + 2 < NKT) RS_STAGE_A(Asb, (kt + 2) * KBK);
            __builtin_amdgcn_s_barrier();
            asm volatile("s_waitcnt lgkmcnt(0)" ::: "memory");
            __builtin_amdgcn_s_setprio(1);
#pragma unroll
            for (int i = 0; i < 8; i++)
#pragma unroll
                for (int j = 2; j < 4; j++)
                    acc[i][j] = __builtin_amdgcn_mfma_f32_16x16x32_bf16(af1[i], bf1[j], acc[i][j], 0, 0, 0);
            __builtin_amdgcn_s_setprio(0);
            if (kt < NKT - 2)       asm volatile("s_waitcnt vmcnt(4)" ::: "memory");
            else if (kt == NKT - 2) asm volatile("s_waitcnt vmcnt(0)" ::: "memory");
            __builtin_amdgcn_s_barrier();
        };

        for (int m = 0; m < NKT / 2; ++m) {
            tile(2 * m,     As0, Bs0, Bs1);
            tile(2 * m + 1, As1, Bs1, Bs0);
        }

#pragma unroll
        for (int i = 0; i < 8; i++)
#pragma unroll
            for (int j = 0; j < 4; j++)
#pragma unroll
                for (int r = 0; r < 4; r++) {
                    const int row = row0 + wr * 128 + i * 16 + kq * 4 + r;
                    const int col = e0 + wc * 64 + j * 16 + lrow;
                    Or[(size_t)row * DIMD + col] =
                        f2b(1.f / (1.f + __expf(-acc[i][j][r])));
                }
#undef RS_STAGE_A
#undef RS_STAGE_B
    }
}

// ---------------------------------------------------------------------------
// Final GEMM: C[n,e] = sum_d A[n,d] * W[e,d], f32 out.
// 256x256 block, 512 threads, 4-phase counted-vmcnt pipeline + swizzle.
// ---------------------------------------------------------------------------
__global__ __launch_bounds__(512, 2)
void gemm_bt(const ushort_t* __restrict__ A,
             const ushort_t* __restrict__ W,
             float* __restrict__ Of)
{
    __shared__ __align__(16) ushort_t As[2][256 * KBK];  // 2 x 32 KB
    __shared__ __align__(16) ushort_t Bs[2][256 * KBK];  // 2 x 32 KB

    const int tid  = threadIdx.x;
    const int lane = tid & 63;
    const int wv   = tid >> 6;
    const int wr   = wv >> 2;
    const int wc   = wv & 3;
    const int lrow = lane & 15;
    const int kq   = lane >> 4;
    const int s8   = lrow & 7;
    const int sw0  = (kq ^ s8) * 8;
    const int sw1  = ((kq + 4) ^ s8) * 8;

    const int row0 = blockIdx.x * 256;
    const int e0   = blockIdx.y * 256;

    const int r_  = tid >> 3;
    const int q_  = ((tid & 7) ^ (r_ & 7)) * 8;
    const size_t aoffs = (size_t)(row0 + r_) * DIMD + q_;
    const size_t boffs = (size_t)(e0 + r_) * DIMD + q_;

#define BT_STAGE_A(dst, k0) do { \
    _Pragma("unroll") \
    for (int it_ = 0; it_ < 4; ++it_) \
        GLL(A + aoffs + (size_t)it_ * 64 * DIMD + (k0), \
            (char*)(dst) + (tid + it_ * 512) * 16); \
} while (0)

#define BT_STAGE_B(dst, k0) do { \
    _Pragma("unroll") \
    for (int it_ = 0; it_ < 4; ++it_) \
        GLL(W + boffs + (size_t)it_ * 64 * DIMD + (k0), \
            (char*)(dst) + (tid + it_ * 512) * 16); \
} while (0)

    f32x4 acc[8][4];
#pragma unroll
    for (int i = 0; i < 8; i++)
#pragma unroll
        for (int j = 0; j < 4; j++)
            acc[i][j] = f32x4{0.f, 0.f, 0.f, 0.f};

    BT_STAGE_A(&As[0][0], 0);
    BT_STAGE_B(&Bs[0][0], 0);
    asm volatile("" ::: "memory");
    BT_STAGE_A(&As[1][0], KBK);
    asm volatile("s_waitcnt vmcnt(4)" ::: "memory");
    __builtin_amdgcn_s_barrier();

    auto tile = [&](int kt, ushort_t* Asb, ushort_t* Bsb, ushort_t* Bsn) {
        bf16x8 af0[8], af1[8], bf0[4], bf1[4];

        // ---- P0
#pragma unroll
        for (int i = 0; i < 8; i++)
            af0[i] = *(const bf16x8*)(Asb + (wr * 128 + i * 16 + lrow) * KBK + sw0);
#pragma unroll
        for (int j = 0; j < 2; j++)
            bf0[j] = *(const bf16x8*)(Bsb + (wc * 64 + j * 16 + lrow) * KBK + sw0);
        if (kt + 1 < NKT) BT_STAGE_B(Bsn, (kt + 1) * KBK);
        __builtin_amdgcn_s_barrier();
        asm volatile("s_waitcnt lgkmcnt(0)" ::: "memory");
        __builtin_amdgcn_s_setprio(1);
#pragma unroll
        for (int i = 0; i < 8; i++)
#pragma unroll
            for (int j = 0; j < 2; j++)
                acc[i][j] = __builtin_amdgcn_mfma_f32_16x16x32_bf16(af0[i], bf0[j], acc[i][j], 0, 0, 0);
        __builtin_amdgcn_s_setprio(0);
        __builtin_amdgcn_s_barrier();

        // ---- P1
#pragma unroll
        for (int j = 2; j < 4; j++)
            bf0[j] = *(const bf16x8*)(Bsb + (wc * 64 + j * 16 + lrow) * KBK + sw0);
        __builtin_amdgcn_s_barrier();
        asm volatile("s_waitcnt lgkmcnt(0)" ::: "memory");
        __builtin_amdgcn_s_setprio(1);
#pragma unroll
        for (int i = 0; i < 8; i++)
#pragma unroll
            for (int j = 2; j < 4; j++)
                acc[i][j] = __builtin_amdgcn_mfma_f32_16x16x32_bf16(af0[i], bf0[j], acc[i][j], 0, 0, 0);
        __builtin_amdgcn_s_setprio(0);
        __builtin_amdgcn_s_barrier();

        // ---- P2
#pragma unroll
        for (int i = 0; i < 8; i++)
            af1[i] = *(const bf16x8*)(Asb + (wr * 128 + i * 16 + lrow) * KBK + sw1);
#pragma unroll
        for (int j = 0; j < 2; j++)
            bf1[j] = *(const bf16x8*)(Bsb + (wc * 64 + j * 16 + lrow) * KBK + sw1);
        __builtin_amdgcn_s_barrier();
        asm volatile("s_waitcnt lgkmcnt(0)" ::: "memory");
        __builtin_amdgcn_s_setprio(1);
#pragma unroll
        for (int i = 0; i < 8; i++)
#pragma unroll
            for (int j = 0; j < 2; j++)
                acc[i][j] = __builtin_amdgcn_mfma_f32_16x16x32_bf16(af1[i], bf1[j], acc[i][j], 0, 0, 0);
        __builtin_amdgcn_s_setprio(0);
        __builtin_amdgcn_s_barrier();

        // ---- P3
#pragma unroll
        for (int j = 2; j < 4; j++)
            bf1[j] = *(const bf16x8*)(Bsb + (wc * 64 + j * 16 + lrow) * KBK + sw1);
        if (kt + 2 < NKT) BT_STAGE_A(Asb, (kt + 2) * KBK);
        __builtin_amdgcn_s_barrier();
        asm volatile("s_waitcnt lgkmcnt(0)" ::: "memory");
        __builtin_amdgcn_s_setprio(1);
#pragma unroll
        for (int i = 0; i < 8; i++)
#pragma unroll
            for (int j = 2; j < 4; j++)
                acc[i][j] = __builtin_amdgcn_mfma_f32_16x16x32_bf16(af1[i], bf1[j], acc[i][j], 0, 0, 0);
        __builtin_amdgcn_s_setprio(0);
        if (kt < NKT - 2)       asm volatile("s_waitcnt vmcnt(4)" ::: "memory");
        else if (kt == NKT - 2) asm volatile("s_waitcnt vmcnt(0)" ::: "memory");
        __builtin_amdgcn_s_barrier();
    };

    for (int m = 0; m < NKT / 2; ++m) {
        tile(2 * m,     &As[0][0], &Bs[0][0], &Bs[1][0]);
        tile(2 * m + 1, &As[1][0], &Bs[1][0], &Bs[0][0]);
    }

#pragma unroll
    for (int i = 0; i < 8; i++)
#pragma unroll
        for (int j = 0; j < 4; j++)
#pragma unroll
            for (int r = 0; r < 4; r++) {
                const int row = row0 + wr * 128 + i * 16 + kq * 4 + r;
                const int col = e0 + wc * 64 + j * 16 + lrow;
                Of[(size_t)row * DIMD + col] = acc[i][j][r];
            }
#undef BT_STAGE_A
#undef BT_STAGE_B
}

// ---------------------------------------------------------------------------
// Emit with self-scan: 256-thread blocks, 4 dims/thread (65536 threads).
// Prefix over raw per-chunk sums, FMA order per dim unchanged.
// ---------------------------------------------------------------------------
__global__ __launch_bounds__(256)
void emit(const ushort_t* __restrict__ kvb, const ushort_t* __restrict__ rb,
          const float* __restrict__ td, const float* __restrict__ tf,
          const float* __restrict__ cs, ushort_t* __restrict__ op)
{
    const int t  = blockIdx.x * 256 + threadIdx.x;   // 65536 threads
    const int d0 = (t & 255) * 4;
    const int bc = t >> 8;
    const int c  = bc & (NCHUNK - 1);
    const int b  = bc >> 6;

    float decay[4], eu[4], dL[4], st[4];
#pragma unroll
    for (int j = 0; j < 4; j++) {
        const float w = -__expf(td[d0 + j]);
        decay[j] = __expf(w);
        dL[j]    = __expf(w * (float)CHUNK);
        eu[j]    = __expf(tf[d0 + j]);
        st[j]    = 0.f;
    }

    const float* csb = cs + ((size_t)b * NCHUNK) * DIMD + d0;
    int cp = 0;
    for (; cp + 4 <= c; cp += 4) {
        const float4 s0 = *(const float4*)(csb + (size_t)(cp + 0) * DIMD);
        const float4 s1 = *(const float4*)(csb + (size_t)(cp + 1) * DIMD);
        const float4 s2 = *(const float4*)(csb + (size_t)(cp + 2) * DIMD);
        const float4 s3 = *(const float4*)(csb + (size_t)(cp + 3) * DIMD);
        st[0] = dL[0] * st[0] + s0.x; st[1] = dL[1] * st[1] + s0.y;
        st[2] = dL[2] * st[2] + s0.z; st[3] = dL[3] * st[3] + s0.w;
        st[0] = dL[0] * st[0] + s1.x; st[1] = dL[1] * st[1] + s1.y;
        st[2] = dL[2] * st[2] + s1.z; st[3] = dL[3] * st[3] + s1.w;
        st[0] = dL[0] * st[0] + s2.x; st[1] = dL[1] * st[1] + s2.y;
        st[2] = dL[2] * st[2] + s2.z; st[3] = dL[3] * st[3] + s2.w;
        st[0] = dL[0] * st[0] + s3.x; st[1] = dL[1] * st[1] + s3.y;
        st[2] = dL[2] * st[2] + s3.z; st[3] = dL[3] * st[3] + s3.w;
    }
    for (; cp < c; cp++) {
        const float4 s0 = *(const float4*)(csb + (size_t)cp * DIMD);
        st[0] = dL[0] * st[0] + s0.x; st[1] = dL[1] * st[1] + s0.y;
        st[2] = dL[2] * st[2] + s0.z; st[3] = dL[3] * st[3] + s0.w;
    }

    size_t off = ((size_t)b * SEQ + (size_t)c * CHUNK) * DIMD + d0;
#pragma unroll 8
    for (int i = 0; i < CHUNK; i++) {
        const u16x4 kv4 = *(const u16x4*)(kvb + off);
        const u16x4 r4  = *(const u16x4*)(rb + off);
        u16x4 o4;
#pragma unroll
        for (int j = 0; j < 4; j++) {
            const float kv = b2f(kv4[j]);
            o4[j] = f2b(b2f(r4[j]) * (st[j] + eu[j] * kv));
            st[j] = decay[j] * st[j] + kv;
        }
        *(u16x4*)(op + off) = o4;
        off += DIMD;
    }
}

// ---------------------------------------------------------------------------
// ws: xb/pbuf 32 MiB + weights 8 MiB + cs 1 MiB = 41 MiB.
// d_out (64 MiB f32) doubles as kvb+rb scratch (dead before final GEMM).
// 4 launches: conv_all -> gemm_kvrs -> emit -> gemm_bt.
// ---------------------------------------------------------------------------
extern "C" void kernel_launch(void* const* d_in, const int* in_sizes, int n_in,
                              void* d_out, int out_size, void* d_ws, size_t ws_size,
                              hipStream_t stream)
{
    const float* x  = (const float*)d_in[0];
    const float* Wk = (const float*)d_in[1];
    const float* Wv = (const float*)d_in[2];
    const float* Wr = (const float*)d_in[3];
    const float* Wo = (const float*)d_in[4];
    const float* td = (const float*)d_in[5];
    const float* tf = (const float*)d_in[6];

    ushort_t* xb  = (ushort_t*)d_ws;                       // 32 MiB; reused as pbuf
    ushort_t* Wb  = xb + (size_t)NTOK * DIMD;              // 8 MiB (4 matrices)
    ushort_t* Wkb = Wb;
    ushort_t* Wvb = Wb + (size_t)DIMD * DIMD;
    ushort_t* Wrb = Wb + 2 * (size_t)DIMD * DIMD;
    ushort_t* Wob = Wb + 3 * (size_t)DIMD * DIMD;
    float*    cs  = (float*)(Wb + 4 * (size_t)DIMD * DIMD); // 1 MiB
    ushort_t* pbuf = xb;

    ushort_t* kvb = (ushort_t*)d_out;                      // 32 MiB scratch
    ushort_t* rb  = kvb + (size_t)NTOK * DIMD;             // 32 MiB scratch
    float*    out = (float*)d_out;

    // 0) all conversions (x + 4 weight matrices), contiguous float4->u16x4
    conv_all<<<(NTOK * (size_t)DIMD / 4 + DIMD * (size_t)DIMD) / 256, 256,
               0, stream>>>(x, Wk, Wv, Wr, Wo, xb, Wb);

    // 1) kv projection (+ per-chunk aggregates) and r projection, one launch
    gemm_kvrs<<<512 + 256, 512, 0, stream>>>(
        xb, Wkb, Wvb, Wrb, td, kvb, rb, cs);

    // 2) emit (self-scans cs) -> pbuf (xb region)
    emit<<<BATCH * NCHUNK * (DIMD / 4) / 256, 256, 0, stream>>>(
        kvb, rb, td, tf, cs, pbuf);

    // 3) out = out_pre @ Wo^T (f32 epilogue, overwrites d_out)
    gemm_bt<<<dim3(NTOK / 256, DIMD / 256), 512, 0, stream>>>(pbuf, Wob, out);
}